// Round 8
// baseline (89.638 us; speedup 1.0000x reference)
//
#include <hip/hip_runtime.h>
#include <math.h>

#define NB 8192
#define NF 512
#define NP 64
#define NC 100
#define NR 16
#define EPSF 1e-4f
#define LOG2E  1.44269504088896340736f

using short8  = __attribute__((ext_vector_type(8))) short;
using floatx4 = __attribute__((ext_vector_type(4))) float;

// pack float4 -> 4 bf16 (truncation); validated R6/R7 (absmax ~2e-6)
__device__ __forceinline__ uint2 pkbf(float4 v) {
  uint2 r;
  r.x = (__float_as_uint(v.y) & 0xffff0000u) | (__float_as_uint(v.x) >> 16);
  r.y = (__float_as_uint(v.w) & 0xffff0000u) | (__float_as_uint(v.z) >> 16);
  return r;
}
__device__ __forceinline__ float rlane(float v, int l) {
  return __uint_as_float(__builtin_amdgcn_readlane(__float_as_uint(v), l));
}

// ---- LDS layout (bytes) ----
// u_l [0,32768) unions GEMM staging: xh [0,4352) wh [4352,21760)
#define OFF_U     0
#define OFF_XH    0
#define OFF_WH    4352
#define OFF_SI    32768
#define OFF_REDB  36864
#define OFF_RMAX  37888
#define OFF_UMAX  38144
#define OFF_XSQL  38400
#define OFF_WSQL  38464
#define OFF_KGAM  38720
#define OFF_ALPH  38976
#define OFF_BINV  39232
#define SMEM_SZ   39488

// One fused kernel, 512 blocks (2/CU) x 256 threads, 16 rows/block.
// GEMM: bf16 MFMA 16x16x32, BK=128 (4 chunks), register prefetch of next
//   chunk's global loads; staging layout stride 136 shorts (17 bank-quads,
//   odd -> conflict-free b128 frag reads).
// Scan (suffix-product form, R7-validated):
//   v' = v1 v2 + 2 om1 om2, om' = 3 om1 om2 (per-step normalizer = pure
//   scale, cancels in final normalize):
//   v_fin[c] = prod_p vt_p[c] + 2 sum_k W_k T_k[c],  T_k = prod_{j>k} vt_j,
//   W_k = 3^(k-1) prod_{j<=k} omt_j  (3^k folded into prefix of 3*omt),
//   om_fin = 3^63 prod omt.
//   NEW layout: one WAVE per row, 2 classes/lane; per-p factors in wave
//   registers broadcast via v_readlane (zero LDS); u via ds_read_b64.
// All reductions butterflies/fixed-order => bitwise deterministic.
__global__ __launch_bounds__(256, 2)
void ds_one(const float* __restrict__ x, const float* __restrict__ w,
            const float* __restrict__ xi, const float* __restrict__ eta,
            const float* __restrict__ beta, float* __restrict__ out)
{
  __shared__ __align__(16) char smem[SMEM_SZ];
  float*  u_l   = (float*)(smem + OFF_U);
  short*  xh    = (short*)(smem + OFF_XH);
  short*  wh    = (short*)(smem + OFF_WH);
  float*  si_l  = (float*)(smem + OFF_SI);
  float*  redb  = (float*)(smem + OFF_REDB);
  float*  rmax  = (float*)(smem + OFF_RMAX);
  float*  umax  = (float*)(smem + OFF_UMAX);
  float*  xsql  = (float*)(smem + OFF_XSQL);
  float*  wsql  = (float*)(smem + OFF_WSQL);
  float*  kgaml = (float*)(smem + OFF_KGAM);
  float*  alphl = (float*)(smem + OFF_ALPH);
  float*  binv  = (float*)(smem + OFF_BINV);

  const int t    = threadIdx.x;
  const int R0   = blockIdx.x * NR;
  const int wv   = t >> 6;                // wave id
  const int ml   = t & 15;                // MFMA m/n lane
  const int qd   = (t & 63) >> 4;         // MFMA quad
  const int xrow = t >> 4, xq = t & 15;   // staging roles
  const int wl   = t & 63;

  // ---- GEMM: D = x . w^T, BK=128, 4 chunks, register prefetch ----
  float xsq_acc = 0.f;
  float wacc[4] = {0.f, 0.f, 0.f, 0.f};
  floatx4 acc = {0.f, 0.f, 0.f, 0.f};
  float4 xr0, xr1, wr[4][2];

  {   // prefetch chunk 0
    const float* xp = &x[(size_t)(R0 + xrow) * NF + xq * 8];
    xr0 = *(const float4*)&xp[0];  xr1 = *(const float4*)&xp[4];
    #pragma unroll
    for (int g = 0; g < 4; ++g) {
      const int row = wv * 16 + g * 4 + (wl >> 4);
      const float* wp = &w[(size_t)row * NF + xq * 8];
      wr[g][0] = *(const float4*)&wp[0];  wr[g][1] = *(const float4*)&wp[4];
    }
  }
  for (int ch = 0; ch < 4; ++ch) {
    __syncthreads();                      // prev chunk's frags consumed
    {
      xsq_acc += xr0.x*xr0.x + xr0.y*xr0.y + xr0.z*xr0.z + xr0.w*xr0.w
               + xr1.x*xr1.x + xr1.y*xr1.y + xr1.z*xr1.z + xr1.w*xr1.w;
      *(uint2*)&xh[xrow * 136 + xq * 8]     = pkbf(xr0);
      *(uint2*)&xh[xrow * 136 + xq * 8 + 4] = pkbf(xr1);
    }
    #pragma unroll
    for (int g = 0; g < 4; ++g) {
      const int row = wv * 16 + g * 4 + (wl >> 4);
      float4 a = wr[g][0], b = wr[g][1];
      wacc[g] += a.x*a.x + a.y*a.y + a.z*a.z + a.w*a.w
               + b.x*b.x + b.y*b.y + b.z*b.z + b.w*b.w;
      *(uint2*)&wh[row * 136 + xq * 8]     = pkbf(a);
      *(uint2*)&wh[row * 136 + xq * 8 + 4] = pkbf(b);
    }
    __syncthreads();
    if (ch < 3) {                         // prefetch next chunk (overlaps MFMA)
      const int kb = (ch + 1) * 128;
      const float* xp = &x[(size_t)(R0 + xrow) * NF + kb + xq * 8];
      xr0 = *(const float4*)&xp[0];  xr1 = *(const float4*)&xp[4];
      #pragma unroll
      for (int g = 0; g < 4; ++g) {
        const int row = wv * 16 + g * 4 + (wl >> 4);
        const float* wp = &w[(size_t)row * NF + kb + xq * 8];
        wr[g][0] = *(const float4*)&wp[0];  wr[g][1] = *(const float4*)&wp[4];
      }
    }
    #pragma unroll
    for (int ks = 0; ks < 4; ++ks) {
      short8 a = *(const short8*)&xh[ml * 136 + ks * 32 + qd * 8];
      short8 b = *(const short8*)&wh[(wv * 16 + ml) * 136 + ks * 32 + qd * 8];
      acc = __builtin_amdgcn_mfma_f32_16x16x32_bf16(a, b, acc, 0, 0, 0);
    }
  }

  // ---- P1: beta partials; xsq/wsq butterflies; kgam/alpha ----
  {
    const int p4 = t >> 2, q4 = t & 3;
    const float* br = beta + p4 * NC + q4 * 25;
    float s = 0.f;
    #pragma unroll 5
    for (int j = 0; j < 25; ++j) { float b = br[j]; s = fmaf(b, b, s); }
    redb[q4 * 64 + p4] = s;
  }
  {
    float s = xsq_acc;
    s += __shfl_xor(s, 1, 64); s += __shfl_xor(s, 2, 64);
    s += __shfl_xor(s, 4, 64); s += __shfl_xor(s, 8, 64);
    if (xq == 0) xsql[xrow] = s;
  }
  #pragma unroll
  for (int g = 0; g < 4; ++g) {
    float s = wacc[g];
    s += __shfl_xor(s, 1, 64); s += __shfl_xor(s, 2, 64);
    s += __shfl_xor(s, 4, 64); s += __shfl_xor(s, 8, 64);
    if (xq == 0) wsql[wv * 16 + g * 4 + (wl >> 4)] = s;
  }
  if (t < 64) {
    float e = eta[t];
    kgaml[t] = -LOG2E * e * e;            // exp(-g*d) = exp2(kgam*d)
    alphl[t] = 1.f / (1.f + __expf(-xi[t]));
  }
  __syncthreads();                        // B1

  // ---- P2: binv; si in MFMA-C layout + per-row 16-lane max ----
  if (t < 64) binv[t] = 1.f / (((redb[t] + redb[64 + t]) + redb[128 + t]) + redb[192 + t]);
  const int pcol = wv * 16 + ml;
  float si4[4];
  {
    const float wq = wsql[pcol], kg = kgaml[pcol], al = alphl[pcol];
    #pragma unroll
    for (int i = 0; i < 4; ++i) {
      float d = xsql[qd * 4 + i] + wq - 2.f * acc[i];
      si4[i] = al * exp2f(kg * d);
    }
    #pragma unroll
    for (int i = 0; i < 4; ++i) {
      float m = si4[i];
      m = fmaxf(m, __shfl_xor(m, 1, 64)); m = fmaxf(m, __shfl_xor(m, 2, 64));
      m = fmaxf(m, __shfl_xor(m, 4, 64)); m = fmaxf(m, __shfl_xor(m, 8, 64));
      if (ml == 0) rmax[(qd * 4 + i) * 4 + wv] = m;
    }
  }
  __syncthreads();                        // B2

  // ---- P3: u fill (over dead staging) + umax; si finalize -> si_l ----
  {
    const int p4 = t >> 2, q4 = t & 3;
    const float bi = binv[p4];
    float um = 0.f;
    #pragma unroll
    for (int i2 = 0; i2 < 8; ++i2) {
      const int q = q4 + 4 * i2;          // col quad 0..31 (NC=100 = quads 0..24)
      float4 uv = make_float4(0.f, 0.f, 0.f, 0.f);
      if (q < 25) {
        const float* br = beta + p4 * NC + q * 4;
        uv.x = br[0]*br[0]*bi; uv.y = br[1]*br[1]*bi;
        uv.z = br[2]*br[2]*bi; uv.w = br[3]*br[3]*bi;
      }
      um = fmaxf(um, fmaxf(fmaxf(uv.x, uv.y), fmaxf(uv.z, uv.w)));
      *(float4*)&u_l[p4 * 128 + q * 4] = uv;
    }
    um = fmaxf(um, __shfl_xor(um, 1, 64));
    um = fmaxf(um, __shfl_xor(um, 2, 64));
    if (q4 == 0) umax[p4] = um;
  }
  #pragma unroll
  for (int i = 0; i < 4; ++i) {
    const int row = qd * 4 + i;
    float m = fmaxf(fmaxf(rmax[row * 4 + 0], rmax[row * 4 + 1]),
                    fmaxf(rmax[row * 4 + 2], rmax[row * 4 + 3]));
    si_l[row * 64 + pcol] = si4[i] * (1.f / (m + EPSF));
  }
  __syncthreads();                        // B3 (last barrier; scan is wave-local)

  // ---- scan: one WAVE per row, 2 classes/lane; 4 rows per wave ----
  const int lane = wl;                    // 0..63; also = p for factor regs
  #pragma unroll 1
  for (int pass = 0; pass < 4; ++pass) {
    const int srow = wv * 4 + pass;
    // per-p factors in registers (lane = p)
    float sp = si_l[srow * 64 + lane];
    float um = umax[lane];
    float om = 1.f - sp;
    float cn = 1.f / fmaf(sp, um, om);    // scale: max_c(vt) ~ 1 -> T <= 1
    float ST = sp * cn, OT = om * cn;
    float P3 = 3.f * OT;                  // prefix of (3*omt) folds 3^k in
    #pragma unroll
    for (int d2 = 1; d2 < 64; d2 <<= 1) {
      float up = __shfl_up(P3, d2, 64);
      if (lane >= d2) P3 *= up;
    }
    float W = (lane == 0) ? 0.f : P3 * (1.f / 9.f);   // 3^(k-1) prod_{j<=k} omt
    float omf = rlane(P3, 63) * (1.f / 3.f);          // 3^63 prod omt

    float T0 = 1.f, T1 = 1.f, S0 = 0.f, S1 = 0.f;
    #pragma unroll 8
    for (int p = 63; p >= 0; --p) {       // S += W_p*T BEFORE T *= vt_p
      float fs = rlane(ST, p);
      float fo = rlane(OT, p);
      float fw = rlane(W,  p);
      float2 u2 = *(const float2*)&u_l[p * 128 + 2 * lane];
      S0 = fmaf(fw, T0, S0);  S1 = fmaf(fw, T1, S1);
      T0 *= fmaf(fs, u2.x, fo);
      T1 *= fmaf(fs, u2.y, fo);
    }
    float m0 = fmaf(2.f, S0, T0) - omf;
    float m1 = fmaf(2.f, S1, T1) - omf;
    if (lane >= 50) { m0 = 0.f; m1 = 0.f; }           // classes >= 100 masked
    float ss = m0 + m1;
    #pragma unroll
    for (int msk = 1; msk < 64; msk <<= 1) ss += __shfl_xor(ss, msk, 64);
    float rn = 1.f / (ss + omf);
    float* orow = &out[(size_t)(R0 + srow) * 101];
    if (lane < 50) {
      orow[2 * lane]     = m0 * rn;
      orow[2 * lane + 1] = m1 * rn;
    } else if (lane == 50) {
      orow[100] = omf * rn;
    }
  }
}

extern "C" void kernel_launch(void* const* d_in, const int* in_sizes, int n_in,
                              void* d_out, int out_size, void* d_ws, size_t ws_size,
                              hipStream_t stream)
{
  const float* x    = (const float*)d_in[0];
  const float* w    = (const float*)d_in[1];
  const float* xi   = (const float*)d_in[2];
  const float* eta  = (const float*)d_in[3];
  const float* beta = (const float*)d_in[4];
  (void)d_ws; (void)ws_size;
  hipLaunchKernelGGL(ds_one, dim3(NB / NR), dim3(256), 0, stream,
                     x, w, xi, eta, beta, (float*)d_out);
}